// Round 3
// baseline (665.408 us; speedup 1.0000x reference)
//
#include <hip/hip_runtime.h>
#include <stdint.h>

// Problem constants (fixed by the reference)
#define BQ   2
#define NQ   8192
#define D1Q  128
#define D2Q  256
#define OUTQ 128
#define CATQ 384   // D1+D2
#define KQ   16

// ---------------------------------------------------------------------------
// Kernel 1: transpose W [OUT, CAT] -> Wt [CAT, OUT]  (tiny)
// ---------------------------------------------------------------------------
__global__ void wt_kernel(const float* __restrict__ W, float* __restrict__ Wt) {
    int flat = blockIdx.x * 256 + threadIdx.x;      // k*OUTQ + o
    if (flat < CATQ * OUTQ) {
        int k = flat >> 7;          // / OUTQ
        int o = flat & (OUTQ - 1);
        Wt[flat] = W[o * CATQ + k];
    }
}

// ---------------------------------------------------------------------------
// Kernel 1b: xyz1 norms, bit-exact numpy order:
//   n = (x*x + y*y) + z*z   with each product separately rounded (no FMA).
// Packed as float4 (x,y,z,n) for single ds_read_b128 in the NN kernel.
// ---------------------------------------------------------------------------
__global__ void norm1_kernel(const float* __restrict__ xyz1,
                             float4* __restrict__ xyz1n) {
    int t = blockIdx.x * 256 + threadIdx.x;
    if (t < BQ * NQ) {
        float x = xyz1[t * 3 + 0];
        float y = xyz1[t * 3 + 1];
        float z = xyz1[t * 3 + 2];
        float n;
        {
            #pragma clang fp contract(off)
            float px = x * x, py = y * y, pz = z * z;
            n = (px + py) + pz;
        }
        xyz1n[t] = make_float4(x, y, z, n);
    }
}

// ---------------------------------------------------------------------------
// Kernel 2: projections.
//   P1Wb[q][o] = bias[o] + points1[q]·Wt[:,o]   (first 128 rows of Wt)
//   P2W [q][o] =            points2[q]·Wt[128:,o]
// ---------------------------------------------------------------------------
__global__ __launch_bounds__(256) void proj_kernel(
        const float* __restrict__ points1, const float* __restrict__ points2,
        const float* __restrict__ Wt, const float* __restrict__ bias,
        float* __restrict__ P1Wb, float* __restrict__ P2W) {
    __shared__ float p1t[16][D1Q];   // 8 KB
    __shared__ float p2t[16][D2Q];   // 16 KB
    const int tid  = threadIdx.x;
    const int row0 = blockIdx.x * 16;

    {
        const float4* s1 = (const float4*)(points1 + (size_t)row0 * D1Q);
        float4* l1 = (float4*)&p1t[0][0];
        #pragma unroll
        for (int v = tid; v < 16 * D1Q / 4; v += 256) l1[v] = s1[v];
        const float4* s2 = (const float4*)(points2 + (size_t)row0 * D2Q);
        float4* l2 = (float4*)&p2t[0][0];
        #pragma unroll
        for (int v = tid; v < 16 * D2Q / 4; v += 256) l2[v] = s2[v];
    }
    __syncthreads();

    const int o = tid & (OUTQ - 1);
    const int h = tid >> 7;          // 0 or 1 -> rows h*8 .. h*8+7

    float acc[8];
    {
        float bv = bias[o];
        #pragma unroll
        for (int j = 0; j < 8; ++j) acc[j] = bv;
    }
    for (int k = 0; k < D1Q; ++k) {
        float w = Wt[k * OUTQ + o];
        #pragma unroll
        for (int j = 0; j < 8; ++j) acc[j] = fmaf(w, p1t[h * 8 + j][k], acc[j]);
    }
    #pragma unroll
    for (int j = 0; j < 8; ++j)
        P1Wb[(size_t)(row0 + h * 8 + j) * OUTQ + o] = acc[j];

    #pragma unroll
    for (int j = 0; j < 8; ++j) acc[j] = 0.0f;
    for (int k = 0; k < D2Q; ++k) {
        float w = Wt[(D1Q + k) * OUTQ + o];
        #pragma unroll
        for (int j = 0; j < 8; ++j) acc[j] = fmaf(w, p2t[h * 8 + j][k], acc[j]);
    }
    #pragma unroll
    for (int j = 0; j < 8; ++j)
        P2W[(size_t)(row0 + h * 8 + j) * OUTQ + o] = acc[j];
}

// ---------------------------------------------------------------------------
// Kernel 3: fused 16-NN + inverse-distance weights + gather/combine.
// One wave per query; 4 queries per 256-thread block.
//
// d2 replicates numpy's arithmetic bit-for-bit (see R2 notes).
// Key = (total_order_map(d2 bits) << 32) | idx -> exact order + tie-break.
//
// R3: wave-global threshold t = min_lanes hi32(a[15]). Any candidate with
// mapped > t provably cannot reach the global top-16 (global-16th-so-far
// <= every lane's a[15], and t only lags behind = stays conservative).
// This makes the expensive 16-deep insert chain execute on ~50/128 steps
// instead of 128/128 (wave-coherent execz skip on the rest).
// ---------------------------------------------------------------------------
__global__ __launch_bounds__(256) void fpn_kernel(
        const float4* __restrict__ xyz1n, const float* __restrict__ xyz2,
        const float* __restrict__ P1Wb, const float* __restrict__ P2W,
        float* __restrict__ out) {
    // union: tile buffer (16 KB) during NN loop; merge spill (34 KB) after.
    __shared__ __align__(16) char smem[4 * 64 * 17 * 8];   // 34816 B
    float4*   xyzt4 = (float4*)smem;                        // 1024 * 16 B
    uint64_t* mball = (uint64_t*)smem;

    const int tid   = threadIdx.x;
    const int lane  = tid & 63;
    const int w     = tid >> 6;
    const int qflat = blockIdx.x * 4 + w;    // 0..16383
    const int b     = qflat >> 13;           // / NQ

    // query coordinates + norm (wave-uniform), numpy rounding order
    const float* qp = xyz2 + (size_t)qflat * 3;
    const float qx = qp[0], qy = qp[1], qz = qp[2];
    float s2;
    {
        #pragma clang fp contract(off)
        float px = qx * qx, py = qy * qy, pz = qz * qz;
        s2 = (px + py) + pz;
    }

    uint64_t a[16];
    #pragma unroll
    for (int i = 0; i < 16; ++i) a[i] = ~0ull;

    uint32_t t = 0xFFFFFFFFu;                // wave-uniform accept threshold

    const float4* xb = xyz1n + (size_t)b * NQ;

    for (int tile = 0; tile < 8; ++tile) {
        __syncthreads();   // protect previous tile's readers
        {
            const float4* s4 = xb + tile * 1024;
            #pragma unroll
            for (int v = tid; v < 1024; v += 256) xyzt4[v] = s4[v];
        }
        __syncthreads();

        const uint32_t base = (uint32_t)tile * 1024u;
        #pragma unroll
        for (int s = 0; s < 16; ++s) {
            const int p = s * 64 + lane;
            float4 pt = xyzt4[p];
            float d2;
            {
                #pragma clang fp contract(off)
                float d0  = pt.x * qx;                 // rounded product
                float dot = fmaf(pt.y, qy, d0);        // explicit FMA chain
                dot       = fmaf(pt.z, qz, dot);
                float tt  = s2 + pt.w;                 // rounded add
                d2        = tt - 2.0f * dot;           // 2*dot exact; rounded sub
            }
            uint32_t bits   = __float_as_uint(d2);
            uint32_t mapped = bits ^ (0x80000000u | (uint32_t)((int32_t)bits >> 31));
            bool cand = (mapped <= t);
            if (__any((int)cand)) {               // wave-coherent skip
                uint64_t key = ((uint64_t)mapped << 32) | (base + (uint32_t)p);
                if (cand && key < a[15]) {        // per-lane insert
                    bool ci = true;               // c15
                    #pragma unroll
                    for (int i = 15; i >= 1; --i) {
                        bool cim1 = key < a[i - 1];
                        a[i] = cim1 ? a[i - 1] : (ci ? key : a[i]);
                        ci = cim1;
                    }
                    a[0] = ci ? key : a[0];
                }
                // refresh threshold (uniform region; all lanes participate)
                uint32_t w15 = (uint32_t)(a[15] >> 32);
                #pragma unroll
                for (int sh = 1; sh < 64; sh <<= 1) {
                    uint32_t o2 = __shfl_xor(w15, sh, 64);
                    w15 = (o2 < w15) ? o2 : w15;
                }
                t = w15;
            }
        }
    }

    // smem reuse boundary: all waves must be done reading xyzt4
    __syncthreads();

    // ---- wave-level 64-way sorted-list merge -> global top-16 ----
    uint64_t* mb = mball + ((size_t)w * 64 + lane) * 17;
    #pragma unroll
    for (int i = 0; i < 16; ++i) mb[i] = a[i];
    mb[16] = ~0ull;                          // sentinel

    uint64_t head  = a[0];
    int      ptr   = 0;
    uint64_t mykey = 0;
    #pragma unroll
    for (int r = 0; r < 16; ++r) {
        uint64_t m = head;
        #pragma unroll
        for (int sh = 1; sh < 64; sh <<= 1) {
            uint64_t o2 = __shfl_xor((unsigned long long)m, sh, 64);
            m = (o2 < m) ? o2 : m;
        }
        if (lane == r) mykey = m;
        if (head == m) { ++ptr; head = mb[ptr]; }   // unique keys: one lane advances
    }

    // ---- inverse-distance weights (lanes 0..15 hold the 16 NN) ----
    uint32_t mhi   = (uint32_t)(mykey >> 32);
    uint32_t rbits = (mhi & 0x80000000u) ? (mhi ^ 0x80000000u) : ~mhi;
    float    d2    = __uint_as_float(rbits);
    int      myidx = (int)(uint32_t)(mykey & 0xFFFFFFFFull);
    float recip = (lane < KQ) ? (1.0f / (d2 + 1e-8f)) : 0.0f;
    float tot = recip;
    #pragma unroll
    for (int sh = 1; sh < 64; sh <<= 1) tot += __shfl_xor(tot, sh, 64);
    float wgt = recip / tot;

    // ---- fused gather + combine: out = P1Wb[q] + sum_k w_k * P2W[idx_k] ----
    const float* prow = P1Wb + (size_t)qflat * OUTQ;
    float acc0 = prow[lane];
    float acc1 = prow[lane + 64];
    const float* p2b = P2W + (size_t)b * NQ * OUTQ;
    #pragma unroll
    for (int k = 0; k < KQ; ++k) {
        int   kk = __shfl(myidx, k, 64);
        float wk = __shfl(wgt,   k, 64);
        const float* row = p2b + (size_t)kk * OUTQ;
        acc0 = fmaf(wk, row[lane],      acc0);
        acc1 = fmaf(wk, row[lane + 64], acc1);
    }
    float* orow = out + (size_t)qflat * OUTQ;
    orow[lane]      = acc0;
    orow[lane + 64] = acc1;
}

// ---------------------------------------------------------------------------
// Launch
// ---------------------------------------------------------------------------
extern "C" void kernel_launch(void* const* d_in, const int* in_sizes, int n_in,
                              void* d_out, int out_size, void* d_ws, size_t ws_size,
                              hipStream_t stream) {
    const float* xyz1    = (const float*)d_in[0];
    const float* xyz2    = (const float*)d_in[1];
    const float* points1 = (const float*)d_in[2];
    const float* points2 = (const float*)d_in[3];
    const float* W       = (const float*)d_in[4];
    const float* bias    = (const float*)d_in[5];
    // d_in[6] = nsample (constant 16, compiled in)

    float* wsf  = (float*)d_ws;
    float* Wt   = wsf;                         // 384*128   = 49152 floats
    float* P1Wb = wsf + 49152;                 // 16384*128 = 2097152 floats
    float* P2W  = P1Wb + 2097152;              // 16384*128
    float4* xyz1n = (float4*)(P2W + 2097152);  // 16384 float4
    // total ws use ≈ 16.7 MB

    wt_kernel<<<(CATQ * OUTQ + 255) / 256, 256, 0, stream>>>(W, Wt);
    norm1_kernel<<<(BQ * NQ + 255) / 256, 256, 0, stream>>>(xyz1, xyz1n);
    proj_kernel<<<(BQ * NQ) / 16, 256, 0, stream>>>(points1, points2, Wt, bias, P1Wb, P2W);
    fpn_kernel<<<(BQ * NQ) / 4, 256, 0, stream>>>(xyz1n, xyz2, P1Wb, P2W, (float*)d_out);
}

// Round 4
// 312.516 us; speedup vs baseline: 2.1292x; 2.1292x over previous
//
#include <hip/hip_runtime.h>
#include <stdint.h>

// Problem constants (fixed by the reference)
#define BQ   2
#define NQ   8192
#define D1Q  128
#define D2Q  256
#define OUTQ 128
#define CATQ 384   // D1+D2
#define KQ   16

// ---------------------------------------------------------------------------
// Kernel 1: transpose W [OUT, CAT] -> Wt [CAT, OUT]  (tiny)
// ---------------------------------------------------------------------------
__global__ void wt_kernel(const float* __restrict__ W, float* __restrict__ Wt) {
    int flat = blockIdx.x * 256 + threadIdx.x;      // k*OUTQ + o
    if (flat < CATQ * OUTQ) {
        int k = flat >> 7;          // / OUTQ
        int o = flat & (OUTQ - 1);
        Wt[flat] = W[o * CATQ + k];
    }
}

// ---------------------------------------------------------------------------
// Kernel 1b: xyz1 norms, bit-exact numpy order:
//   n = (x*x + y*y) + z*z   with each product separately rounded (no FMA).
// ---------------------------------------------------------------------------
__global__ void norm1_kernel(const float* __restrict__ xyz1,
                             float4* __restrict__ xyz1n) {
    int t = blockIdx.x * 256 + threadIdx.x;
    if (t < BQ * NQ) {
        float x = xyz1[t * 3 + 0];
        float y = xyz1[t * 3 + 1];
        float z = xyz1[t * 3 + 2];
        float n;
        {
            #pragma clang fp contract(off)
            float px = x * x, py = y * y, pz = z * z;
            n = (px + py) + pz;
        }
        xyz1n[t] = make_float4(x, y, z, n);
    }
}

// ---------------------------------------------------------------------------
// Kernel 2: projections (unchanged from R2).
// ---------------------------------------------------------------------------
__global__ __launch_bounds__(256) void proj_kernel(
        const float* __restrict__ points1, const float* __restrict__ points2,
        const float* __restrict__ Wt, const float* __restrict__ bias,
        float* __restrict__ P1Wb, float* __restrict__ P2W) {
    __shared__ float p1t[16][D1Q];   // 8 KB
    __shared__ float p2t[16][D2Q];   // 16 KB
    const int tid  = threadIdx.x;
    const int row0 = blockIdx.x * 16;

    {
        const float4* s1 = (const float4*)(points1 + (size_t)row0 * D1Q);
        float4* l1 = (float4*)&p1t[0][0];
        #pragma unroll
        for (int v = tid; v < 16 * D1Q / 4; v += 256) l1[v] = s1[v];
        const float4* s2 = (const float4*)(points2 + (size_t)row0 * D2Q);
        float4* l2 = (float4*)&p2t[0][0];
        #pragma unroll
        for (int v = tid; v < 16 * D2Q / 4; v += 256) l2[v] = s2[v];
    }
    __syncthreads();

    const int o = tid & (OUTQ - 1);
    const int h = tid >> 7;          // 0 or 1 -> rows h*8 .. h*8+7

    float acc[8];
    {
        float bv = bias[o];
        #pragma unroll
        for (int j = 0; j < 8; ++j) acc[j] = bv;
    }
    for (int k = 0; k < D1Q; ++k) {
        float w = Wt[k * OUTQ + o];
        #pragma unroll
        for (int j = 0; j < 8; ++j) acc[j] = fmaf(w, p1t[h * 8 + j][k], acc[j]);
    }
    #pragma unroll
    for (int j = 0; j < 8; ++j)
        P1Wb[(size_t)(row0 + h * 8 + j) * OUTQ + o] = acc[j];

    #pragma unroll
    for (int j = 0; j < 8; ++j) acc[j] = 0.0f;
    for (int k = 0; k < D2Q; ++k) {
        float w = Wt[(D1Q + k) * OUTQ + o];
        #pragma unroll
        for (int j = 0; j < 8; ++j) acc[j] = fmaf(w, p2t[h * 8 + j][k], acc[j]);
    }
    #pragma unroll
    for (int j = 0; j < 8; ++j)
        P2W[(size_t)(row0 + h * 8 + j) * OUTQ + o] = acc[j];
}

// numpy-exact squared distance (same rounding as the reference BLAS path)
__device__ __forceinline__ float npy_d2(float4 pt, float qx, float qy, float qz,
                                        float s2) {
    #pragma clang fp contract(off)
    float d0  = pt.x * qx;                 // rounded product
    float dot = fmaf(pt.y, qy, d0);        // explicit FMA chain
    dot       = fmaf(pt.z, qz, dot);
    float tt  = s2 + pt.w;                 // rounded add
    return tt - 2.0f * dot;                // 2*dot exact; rounded sub
}

// ---------------------------------------------------------------------------
// Kernel 3: fused 16-NN + weights + gather/combine.  One wave per query.
//
// R4 structure:
//  Phase 1 (branchless): per-lane min d2 over its 128 candidates; bitonic
//    sort of the 64 lane-minima by shuffles; t_hat = rank-15 value.
//    t_hat >= global 16th distance (16 smallest lane minima are 16 distinct
//    candidates) -> rejecting d2 > t_hat is provably safe.
//  Phase 2: re-scan; chunks of 8 steps computed branchlessly; uniform 8-bit
//    fire mask; only fired steps run the (predicated, R2-proven) 64-bit-key
//    insert chain. t_hat is FIXED -> no refresh, no LDS-pipe ops in the gate.
//  Merge / weights / epilogue: identical to R2.
// ---------------------------------------------------------------------------
__global__ __launch_bounds__(256) void fpn_kernel(
        const float4* __restrict__ xyz1n, const float* __restrict__ xyz2,
        const float* __restrict__ P1Wb, const float* __restrict__ P2W,
        float* __restrict__ out) {
    // union: tile buffer (16 KB) during scans; merge spill (34 KB) after.
    __shared__ __align__(16) char smem[4 * 64 * 17 * 8];   // 34816 B
    float4*   xyzt4 = (float4*)smem;                        // 1024 * 16 B
    uint64_t* mball = (uint64_t*)smem;

    const int tid   = threadIdx.x;
    const int lane  = tid & 63;
    const int w     = tid >> 6;
    const int qflat = blockIdx.x * 4 + w;    // 0..16383
    const int b     = qflat >> 13;           // / NQ

    const float* qp = xyz2 + (size_t)qflat * 3;
    const float qx = qp[0], qy = qp[1], qz = qp[2];
    float s2;
    {
        #pragma clang fp contract(off)
        float px = qx * qx, py = qy * qy, pz = qz * qz;
        s2 = (px + py) + pz;
    }

    const float4* xb = xyz1n + (size_t)b * NQ;

    // ---------------- Phase 1: branchless lane-min scan ----------------
    float mymin = __uint_as_float(0x7F800000u);   // +inf
    for (int tile = 0; tile < 8; ++tile) {
        __syncthreads();
        {
            const float4* s4 = xb + tile * 1024;
            #pragma unroll
            for (int v = tid; v < 1024; v += 256) xyzt4[v] = s4[v];
        }
        __syncthreads();
        #pragma unroll
        for (int s = 0; s < 16; ++s) {
            float4 pt = xyzt4[s * 64 + lane];
            mymin = fminf(mymin, npy_d2(pt, qx, qy, qz, s2));
        }
    }

    // bitonic sort of 64 lane minima (ascending by lane); t_hat = rank 15
    float x = mymin;
    #pragma unroll
    for (int k = 2; k <= 64; k <<= 1) {
        #pragma unroll
        for (int j = k >> 1; j > 0; j >>= 1) {
            float px = __shfl_xor(x, j, 64);
            bool keep_min = (((lane & j) == 0) == ((lane & k) == 0));
            float mn = fminf(x, px), mx = fmaxf(x, px);
            x = keep_min ? mn : mx;
        }
    }
    const float that = __shfl(x, 15, 64);    // wave-uniform threshold

    // ---------------- Phase 2: gated exact top-16 ----------------
    uint64_t a[16];
    #pragma unroll
    for (int i = 0; i < 16; ++i) a[i] = ~0ull;

    for (int tile = 0; tile < 8; ++tile) {
        __syncthreads();
        {
            const float4* s4 = xb + tile * 1024;
            #pragma unroll
            for (int v = tid; v < 1024; v += 256) xyzt4[v] = s4[v];
        }
        __syncthreads();

        const uint32_t base = (uint32_t)tile * 1024u;
        #pragma unroll
        for (int c = 0; c < 2; ++c) {            // two chunks of 8 steps
            float d2s[8];
            #pragma unroll
            for (int u = 0; u < 8; ++u) {
                float4 pt = xyzt4[(c * 8 + u) * 64 + lane];
                d2s[u] = npy_d2(pt, qx, qy, qz, s2);
            }
            unsigned fm = 0;
            #pragma unroll
            for (int u = 0; u < 8; ++u)
                if (__any((int)(d2s[u] <= that))) fm |= (1u << u);
            #pragma unroll
            for (int u = 0; u < 8; ++u) {
                if (fm & (1u << u)) {            // uniform mini-branch
                    uint32_t bits   = __float_as_uint(d2s[u]);
                    uint32_t mapped = bits ^ (0x80000000u |
                                      (uint32_t)((int32_t)bits >> 31));
                    uint32_t idx  = base + (uint32_t)((c * 8 + u) * 64 + lane);
                    bool     cand = (d2s[u] <= that);
                    uint64_t key  = cand ? (((uint64_t)mapped << 32) | idx)
                                         : ~0ull;
                    if (key < a[15]) {           // predicated insert chain
                        bool ci = true;
                        #pragma unroll
                        for (int i = 15; i >= 1; --i) {
                            bool cim1 = key < a[i - 1];
                            a[i] = cim1 ? a[i - 1] : (ci ? key : a[i]);
                            ci = cim1;
                        }
                        a[0] = ci ? key : a[0];
                    }
                }
            }
        }
    }

    // smem reuse boundary
    __syncthreads();

    // ---- wave-level 64-way sorted-list merge -> global top-16 (R2) ----
    uint64_t* mb = mball + ((size_t)w * 64 + lane) * 17;
    #pragma unroll
    for (int i = 0; i < 16; ++i) mb[i] = a[i];
    mb[16] = ~0ull;                          // sentinel

    uint64_t head  = a[0];
    int      ptr   = 0;
    uint64_t mykey = 0;
    #pragma unroll
    for (int r = 0; r < 16; ++r) {
        uint64_t m = head;
        #pragma unroll
        for (int sh = 1; sh < 64; sh <<= 1) {
            uint64_t o2 = __shfl_xor((unsigned long long)m, sh, 64);
            m = (o2 < m) ? o2 : m;
        }
        if (lane == r) mykey = m;
        if (head == m) { ++ptr; head = mb[ptr]; }   // unique keys
    }

    // ---- inverse-distance weights (lanes 0..15 hold the 16 NN) ----
    uint32_t mhi   = (uint32_t)(mykey >> 32);
    uint32_t rbits = (mhi & 0x80000000u) ? (mhi ^ 0x80000000u) : ~mhi;
    float    d2w   = __uint_as_float(rbits);
    int      myidx = (int)(uint32_t)(mykey & 0xFFFFFFFFull);
    float recip = (lane < KQ) ? (1.0f / (d2w + 1e-8f)) : 0.0f;
    float tot = recip;
    #pragma unroll
    for (int sh = 1; sh < 64; sh <<= 1) tot += __shfl_xor(tot, sh, 64);
    float wgt = recip / tot;

    // ---- fused gather + combine ----
    const float* prow = P1Wb + (size_t)qflat * OUTQ;
    float acc0 = prow[lane];
    float acc1 = prow[lane + 64];
    const float* p2b = P2W + (size_t)b * NQ * OUTQ;
    #pragma unroll
    for (int k = 0; k < KQ; ++k) {
        int   kk = __shfl(myidx, k, 64);
        float wk = __shfl(wgt,   k, 64);
        const float* row = p2b + (size_t)kk * OUTQ;
        acc0 = fmaf(wk, row[lane],      acc0);
        acc1 = fmaf(wk, row[lane + 64], acc1);
    }
    float* orow = out + (size_t)qflat * OUTQ;
    orow[lane]      = acc0;
    orow[lane + 64] = acc1;
}

// ---------------------------------------------------------------------------
// Launch
// ---------------------------------------------------------------------------
extern "C" void kernel_launch(void* const* d_in, const int* in_sizes, int n_in,
                              void* d_out, int out_size, void* d_ws, size_t ws_size,
                              hipStream_t stream) {
    const float* xyz1    = (const float*)d_in[0];
    const float* xyz2    = (const float*)d_in[1];
    const float* points1 = (const float*)d_in[2];
    const float* points2 = (const float*)d_in[3];
    const float* W       = (const float*)d_in[4];
    const float* bias    = (const float*)d_in[5];

    float* wsf  = (float*)d_ws;
    float* Wt   = wsf;                         // 384*128   = 49152 floats
    float* P1Wb = wsf + 49152;                 // 16384*128 = 2097152 floats
    float* P2W  = P1Wb + 2097152;              // 16384*128
    float4* xyz1n = (float4*)(P2W + 2097152);  // 16384 float4

    wt_kernel<<<(CATQ * OUTQ + 255) / 256, 256, 0, stream>>>(W, Wt);
    norm1_kernel<<<(BQ * NQ + 255) / 256, 256, 0, stream>>>(xyz1, xyz1n);
    proj_kernel<<<(BQ * NQ) / 16, 256, 0, stream>>>(points1, points2, Wt, bias, P1Wb, P2W);
    fpn_kernel<<<(BQ * NQ) / 4, 256, 0, stream>>>(xyz1n, xyz2, P1Wb, P2W, (float*)d_out);
}

// Round 5
// 218.428 us; speedup vs baseline: 3.0464x; 1.4308x over previous
//
#include <hip/hip_runtime.h>
#include <stdint.h>

// Problem constants (fixed by the reference)
#define BQ   2
#define NQ   8192
#define D1Q  128
#define D2Q  256
#define OUTQ 128
#define CATQ 384   // D1+D2
#define KQ   16

// ---------------------------------------------------------------------------
// Kernel 1: transpose W [OUT, CAT] -> Wt [CAT, OUT]  (tiny)
// ---------------------------------------------------------------------------
__global__ void wt_kernel(const float* __restrict__ W, float* __restrict__ Wt) {
    int flat = blockIdx.x * 256 + threadIdx.x;      // k*OUTQ + o
    if (flat < CATQ * OUTQ) {
        int k = flat >> 7;          // / OUTQ
        int o = flat & (OUTQ - 1);
        Wt[flat] = W[o * CATQ + k];
    }
}

// ---------------------------------------------------------------------------
// Kernel 1b: xyz1 norms, bit-exact numpy order.
// ---------------------------------------------------------------------------
__global__ void norm1_kernel(const float* __restrict__ xyz1,
                             float4* __restrict__ xyz1n) {
    int t = blockIdx.x * 256 + threadIdx.x;
    if (t < BQ * NQ) {
        float x = xyz1[t * 3 + 0];
        float y = xyz1[t * 3 + 1];
        float z = xyz1[t * 3 + 2];
        float n;
        {
            #pragma clang fp contract(off)
            float px = x * x, py = y * y, pz = z * z;
            n = (px + py) + pz;
        }
        xyz1n[t] = make_float4(x, y, z, n);
    }
}

// ---------------------------------------------------------------------------
// Kernel 2: projections (unchanged from R2).
// ---------------------------------------------------------------------------
__global__ __launch_bounds__(256) void proj_kernel(
        const float* __restrict__ points1, const float* __restrict__ points2,
        const float* __restrict__ Wt, const float* __restrict__ bias,
        float* __restrict__ P1Wb, float* __restrict__ P2W) {
    __shared__ float p1t[16][D1Q];   // 8 KB
    __shared__ float p2t[16][D2Q];   // 16 KB
    const int tid  = threadIdx.x;
    const int row0 = blockIdx.x * 16;

    {
        const float4* s1 = (const float4*)(points1 + (size_t)row0 * D1Q);
        float4* l1 = (float4*)&p1t[0][0];
        #pragma unroll
        for (int v = tid; v < 16 * D1Q / 4; v += 256) l1[v] = s1[v];
        const float4* s2 = (const float4*)(points2 + (size_t)row0 * D2Q);
        float4* l2 = (float4*)&p2t[0][0];
        #pragma unroll
        for (int v = tid; v < 16 * D2Q / 4; v += 256) l2[v] = s2[v];
    }
    __syncthreads();

    const int o = tid & (OUTQ - 1);
    const int h = tid >> 7;          // 0 or 1 -> rows h*8 .. h*8+7

    float acc[8];
    {
        float bv = bias[o];
        #pragma unroll
        for (int j = 0; j < 8; ++j) acc[j] = bv;
    }
    for (int k = 0; k < D1Q; ++k) {
        float w = Wt[k * OUTQ + o];
        #pragma unroll
        for (int j = 0; j < 8; ++j) acc[j] = fmaf(w, p1t[h * 8 + j][k], acc[j]);
    }
    #pragma unroll
    for (int j = 0; j < 8; ++j)
        P1Wb[(size_t)(row0 + h * 8 + j) * OUTQ + o] = acc[j];

    #pragma unroll
    for (int j = 0; j < 8; ++j) acc[j] = 0.0f;
    for (int k = 0; k < D2Q; ++k) {
        float w = Wt[(D1Q + k) * OUTQ + o];
        #pragma unroll
        for (int j = 0; j < 8; ++j) acc[j] = fmaf(w, p2t[h * 8 + j][k], acc[j]);
    }
    #pragma unroll
    for (int j = 0; j < 8; ++j)
        P2W[(size_t)(row0 + h * 8 + j) * OUTQ + o] = acc[j];
}

// numpy-exact squared distance (same rounding as the reference BLAS path)
__device__ __forceinline__ float npy_d2(float4 pt, float qx, float qy, float qz,
                                        float s2) {
    #pragma clang fp contract(off)
    float d0  = pt.x * qx;                 // rounded product
    float dot = fmaf(pt.y, qy, d0);        // explicit FMA chain
    dot       = fmaf(pt.z, qz, dot);
    float tt  = s2 + pt.w;                 // rounded add
    return tt - 2.0f * dot;                // 2*dot exact; rounded sub
}

// full ascending bitonic sort of one uint64 per lane across the wave
__device__ __forceinline__ uint64_t sort64(uint64_t x, int lane) {
    #pragma unroll
    for (int k = 2; k <= 64; k <<= 1) {
        #pragma unroll
        for (int j = k >> 1; j > 0; j >>= 1) {
            uint64_t p = __shfl_xor((unsigned long long)x, j, 64);
            bool keep_min = (((lane & j) == 0) == ((lane & k) == 0));
            bool pless    = p < x;
            x = (pless == keep_min) ? p : x;   // ties: same value either way
        }
    }
    return x;
}

// ---------------------------------------------------------------------------
// Kernel 3: fused 16-NN + weights + gather/combine.  One wave per query.
//
// R5 structure:
//  Phase 1 (branchless): lane-min scan + 64-lane float bitonic;
//    t_hat = rank-15 lane-min >= global 16th distance (provably safe gate).
//  Phase 2 (branchless): stream-compact all candidates with d2 <= t_hat
//    (~20-40 per query) into a 128-slot per-wave LDS buffer via
//    ballot+mbcnt positioning. No insert chains.
//  Selection: one 64-lane 64-bit bitonic sort (pad ~0) -> lanes 0..15 hold
//    the exact top-16 ascending (idx tie-break inside the key). Uniform
//    fallback (3 sorts) covers 64 < cnt <= 128; cnt >= 16 is guaranteed.
// ---------------------------------------------------------------------------
__global__ __launch_bounds__(256) void fpn_kernel(
        const float4* __restrict__ xyz1n, const float* __restrict__ xyz2,
        const float* __restrict__ P1Wb, const float* __restrict__ P2W,
        float* __restrict__ out) {
    __shared__ __align__(16) float4 xyzt4[1024];     // 16 KB tile
    __shared__ uint64_t wball[4][128];               // 4 KB candidate spill

    const int tid   = threadIdx.x;
    const int lane  = tid & 63;
    const int w     = tid >> 6;
    const int qflat = blockIdx.x * 4 + w;    // 0..16383
    const int b     = qflat >> 13;           // / NQ

    const float* qp = xyz2 + (size_t)qflat * 3;
    const float qx = qp[0], qy = qp[1], qz = qp[2];
    float s2;
    {
        #pragma clang fp contract(off)
        float px = qx * qx, py = qy * qy, pz = qz * qz;
        s2 = (px + py) + pz;
    }

    const float4* xb = xyz1n + (size_t)b * NQ;

    // ---------------- Phase 1: branchless lane-min scan ----------------
    float mymin = __uint_as_float(0x7F800000u);   // +inf
    for (int tile = 0; tile < 8; ++tile) {
        __syncthreads();
        {
            const float4* s4 = xb + tile * 1024;
            #pragma unroll
            for (int v = tid; v < 1024; v += 256) xyzt4[v] = s4[v];
        }
        __syncthreads();
        #pragma unroll
        for (int s = 0; s < 16; ++s) {
            float4 pt = xyzt4[s * 64 + lane];
            mymin = fminf(mymin, npy_d2(pt, qx, qy, qz, s2));
        }
    }

    // bitonic sort of 64 lane minima; t_hat = rank 15
    {
        float x = mymin;
        #pragma unroll
        for (int k = 2; k <= 64; k <<= 1) {
            #pragma unroll
            for (int j = k >> 1; j > 0; j >>= 1) {
                float px = __shfl_xor(x, j, 64);
                bool keep_min = (((lane & j) == 0) == ((lane & k) == 0));
                float mn = fminf(x, px), mx = fmaxf(x, px);
                x = keep_min ? mn : mx;
            }
        }
        mymin = x;
    }
    const float that = __shfl(mymin, 15, 64);    // wave-uniform threshold

    // ---------------- Phase 2: branchless candidate compaction ----------------
    uint64_t* wbuf = wball[w];
    uint32_t  cnt  = 0;
    // tile 7 is still resident in LDS from phase 1 -> scan it first, no restage
    for (int tt = 0; tt < 8; ++tt) {
        const int tile = 7 - tt;
        if (tt > 0) {
            __syncthreads();
            const float4* s4 = xb + tile * 1024;
            #pragma unroll
            for (int v = tid; v < 1024; v += 256) xyzt4[v] = s4[v];
            __syncthreads();
        }
        const uint32_t base = (uint32_t)tile * 1024u;
        #pragma unroll
        for (int s = 0; s < 16; ++s) {
            float4 pt = xyzt4[s * 64 + lane];
            float  d2 = npy_d2(pt, qx, qy, qz, s2);
            bool   v  = (d2 <= that);
            uint64_t mask = __ballot((int)v);
            uint32_t below = __builtin_amdgcn_mbcnt_hi(
                                 (uint32_t)(mask >> 32),
                                 __builtin_amdgcn_mbcnt_lo((uint32_t)mask, 0u));
            uint32_t pos = cnt + below;
            if (v && pos < 128u) {
                uint32_t bits   = __float_as_uint(d2);
                uint32_t mapped = bits ^ (0x80000000u |
                                  (uint32_t)((int32_t)bits >> 31));
                wbuf[pos] = ((uint64_t)mapped << 32) |
                            (uint64_t)(base + (uint32_t)(s * 64 + lane));
            }
            cnt += (uint32_t)__popcll(mask);
        }
    }

    // ---------------- Selection: bitonic top-16 ----------------
    uint64_t mykey;
    if (cnt <= 64u) {                                  // normal path
        uint64_t k0 = (lane < (int)cnt) ? wbuf[lane] : ~0ull;
        mykey = sort64(k0, lane);
    } else {                                           // uniform fallback
        uint32_t cc = cnt > 128u ? 128u : cnt;
        uint64_t k0 = wbuf[lane];                      // lanes 0..63 valid
        uint64_t k1 = (lane + 64 < (int)cc) ? wbuf[lane + 64] : ~0ull;
        k0 = sort64(k0, lane);
        k1 = sort64(k1, lane);
        uint64_t t1 = __shfl((unsigned long long)k1, lane & 15, 64);
        uint64_t km = (lane < 16) ? k0 : ((lane < 32) ? t1 : ~0ull);
        mykey = sort64(km, lane);
    }

    // ---- inverse-distance weights (lanes 0..15 hold the 16 NN) ----
    uint32_t mhi   = (uint32_t)(mykey >> 32);
    uint32_t rbits = (mhi & 0x80000000u) ? (mhi ^ 0x80000000u) : ~mhi;
    float    d2w   = __uint_as_float(rbits);
    int      myidx = (int)(uint32_t)(mykey & 0xFFFFFFFFull);
    float recip = (lane < KQ) ? (1.0f / (d2w + 1e-8f)) : 0.0f;
    float tot = recip;
    #pragma unroll
    for (int sh = 1; sh < 64; sh <<= 1) tot += __shfl_xor(tot, sh, 64);
    float wgt = recip / tot;

    // ---- fused gather + combine ----
    const float* prow = P1Wb + (size_t)qflat * OUTQ;
    float acc0 = prow[lane];
    float acc1 = prow[lane + 64];
    const float* p2b = P2W + (size_t)b * NQ * OUTQ;
    #pragma unroll
    for (int k = 0; k < KQ; ++k) {
        int   kk = __shfl(myidx, k, 64);
        float wk = __shfl(wgt,   k, 64);
        const float* row = p2b + (size_t)kk * OUTQ;
        acc0 = fmaf(wk, row[lane],      acc0);
        acc1 = fmaf(wk, row[lane + 64], acc1);
    }
    float* orow = out + (size_t)qflat * OUTQ;
    orow[lane]      = acc0;
    orow[lane + 64] = acc1;
}

// ---------------------------------------------------------------------------
// Launch
// ---------------------------------------------------------------------------
extern "C" void kernel_launch(void* const* d_in, const int* in_sizes, int n_in,
                              void* d_out, int out_size, void* d_ws, size_t ws_size,
                              hipStream_t stream) {
    const float* xyz1    = (const float*)d_in[0];
    const float* xyz2    = (const float*)d_in[1];
    const float* points1 = (const float*)d_in[2];
    const float* points2 = (const float*)d_in[3];
    const float* W       = (const float*)d_in[4];
    const float* bias    = (const float*)d_in[5];

    float* wsf  = (float*)d_ws;
    float* Wt   = wsf;                         // 384*128   = 49152 floats
    float* P1Wb = wsf + 49152;                 // 16384*128 = 2097152 floats
    float* P2W  = P1Wb + 2097152;              // 16384*128
    float4* xyz1n = (float4*)(P2W + 2097152);  // 16384 float4

    wt_kernel<<<(CATQ * OUTQ + 255) / 256, 256, 0, stream>>>(W, Wt);
    norm1_kernel<<<(BQ * NQ + 255) / 256, 256, 0, stream>>>(xyz1, xyz1n);
    proj_kernel<<<(BQ * NQ) / 16, 256, 0, stream>>>(points1, points2, Wt, bias, P1Wb, P2W);
    fpn_kernel<<<(BQ * NQ) / 4, 256, 0, stream>>>(xyz1n, xyz2, P1Wb, P2W, (float*)d_out);
}